// Round 11
// baseline (1404.945 us; speedup 1.0000x reference)
//
#include <hip/hip_runtime.h>
#include <hip/hip_bf16.h>

// GeoMapNet fused forward, MFMA bf16, LDS-resident fp32 master (R17).
// R17 = R15/R16 resubmitted verbatim (both prior benches died at
// CONTAINER ACQUISITION - no timing fields, never compiled/ran).
// R15 = R14 (1201 us: R6 structure + setprio + exp2 softmax) with the FFN
// restructured as a half-chunk PING-PONG: 6 halves {96x5, 32} of the 512
// hidden cols, double-buffered (2 x 48x96x2 = 18432 B in the same C
// region). Each phase: F1(half p) || F2(half p-1) - F1's global weight
// loads are issued first and their ~250cy latency is filled by F2's MFMA
// and the interleaved F1 MFMA. This achieves what the R8/R9/R11 register
// prefetch attempted WITHOUT exceeding the 84-arch-VGPR cap (per-phase
// peak ~75: fa16+fb16+wA/wB32+hf12; ff/facc live in AGPRs). Costs +1
// barrier/layer (7 vs 6 in FFN).
// Register model (R6-R14): unified 170/wave at (256,3) splits ~84 arch +
// ~84 acc; any arch-side liveness added on top of rolling prefetch spills.

typedef __attribute__((ext_vector_type(8))) short short8;   // 8 bf16
typedef __attribute__((ext_vector_type(4))) float floatx4;  // MFMA C/D

namespace {
constexpr int S = 3, DIN = 72, D = 100, FF = 512, L = 8, CLS = 40;
constexpr int NB = 16, R = 48, NT = 256;
constexpr int LDA = 136;   // sA row stride (shorts): 16B-aligned, bank-rotated
// DH^-0.5 * log2(e): softmax via exp2 (identical result, saves a mul/exp)
constexpr float SCALE_L2E = 0.45622024f;

// d_ws element offsets (bf16). Fragment block = 64 lanes x 8 bf16.
constexpr int PL_QKVO = 7 * 4 * 512;                 // per layer
constexpr int WQ_OFF = 0;
constexpr int WK_OFF = WQ_OFF + L * PL_QKVO;
constexpr int WV_OFF = WK_OFF + L * PL_QKVO;
constexpr int WO_OFF = WV_OFF + L * PL_QKVO;
constexpr int PL_W1 = 32 * 4 * 512;
constexpr int W1_OFF = WO_OFF + L * PL_QKVO;
constexpr int PL_W2 = 7 * 16 * 512;
constexpr int W2_OFF = W1_OFF + L * PL_W1;
constexpr int WE_OFF = W2_OFF + L * PL_W2;           // 7 nt x 3 ks
}  // namespace

#define MFMA_BF16 __builtin_amdgcn_mfma_f32_16x16x32_bf16

__device__ __forceinline__ unsigned short f2bf(float f) {  // RTNE (prep only)
  unsigned int u = __float_as_uint(f);
  u = u + 0x7fffu + ((u >> 16) & 1u);
  return (unsigned short)(u >> 16);
}

__device__ __forceinline__ unsigned pkbf(float a, float b) {  // packed cvt
  __hip_bfloat162 h = __float22bfloat162_rn(make_float2(a, b));
  return *reinterpret_cast<unsigned*>(&h);
}

__device__ __forceinline__ void st_bf4(unsigned short* p, floatx4 v) {
  *reinterpret_cast<uint2*>(p) = make_uint2(pkbf(v.x, v.y), pkbf(v.z, v.w));
}

__device__ __forceinline__ void load10(float* o, const unsigned short* p) {
  const unsigned* u = (const unsigned*)p;  // 4B-aligned (even col)
#pragma unroll
  for (int w = 0; w < 5; ++w) {
    unsigned x = u[w];
    o[2 * w] = __uint_as_float(x << 16);
    o[2 * w + 1] = __uint_as_float(x & 0xffff0000u);
  }
}

__device__ __forceinline__ void ldwf4(const unsigned short* base, short8* o) {
#pragma unroll
  for (int ks = 0; ks < 4; ++ks) o[ks] = *(const short8*)(base + ks * 512);
}

// LayerNorm over 48 rows of 100; 4 lanes/row (192 threads), vectorized.
__device__ __forceinline__ void ln_rows(float* xrow, const float* srow,
                                        const float* __restrict__ g,
                                        const float* __restrict__ b,
                                        unsigned short* sArow, int ln,
                                        int cnt) {
  floatx4 v[7];
  float sum = 0.f;
#pragma unroll
  for (int i = 0; i < 7; ++i)
    if (i < cnt) {
      const int col = i * 16 + ln * 4;
      floatx4 t = *(const floatx4*)(xrow + col) + *(const floatx4*)(srow + col);
      v[i] = t;
      sum += t.x + t.y + t.z + t.w;
    }
  sum += __shfl_xor(sum, 1, 4);
  sum += __shfl_xor(sum, 2, 4);
  const float mean = sum * 0.01f;
  float var = 0.f;
#pragma unroll
  for (int i = 0; i < 7; ++i)
    if (i < cnt) {
      floatx4 d = v[i] - mean;
      var += d.x * d.x + d.y * d.y + d.z * d.z + d.w * d.w;
    }
  var += __shfl_xor(var, 1, 4);
  var += __shfl_xor(var, 2, 4);
  const float rstd = rsqrtf(var * 0.01f + 1e-5f);
#pragma unroll
  for (int i = 0; i < 7; ++i)
    if (i < cnt) {
      const int col = i * 16 + ln * 4;
      floatx4 o = (v[i] - mean) * rstd * *(const floatx4*)(g + col) +
                  *(const floatx4*)(b + col);
      *(floatx4*)(xrow + col) = o;
      st_bf4(sArow + col, o);
    }
}

// ------------- weight pre-pack: fp32 row-major -> bf16 fragment blocks -----
__global__ void prep_weights(const float* __restrict__ Wq, const float* __restrict__ Wk,
                             const float* __restrict__ Wv, const float* __restrict__ Wo,
                             const float* __restrict__ W1, const float* __restrict__ W2,
                             const float* __restrict__ We,
                             unsigned short* __restrict__ ws) {
  const int gid = blockIdx.x * 256 + threadIdx.x;
  constexpr int T_QKVO = 8 * 7 * 4 * 64;  // 14336
  constexpr int T_W1 = 8 * 32 * 4 * 64;   // 65536
  constexpr int T_W2 = 8 * 7 * 16 * 64;   // 57344
  constexpr int T_WE = 7 * 3 * 64;        // 1344
  if (gid >= 4 * T_QKVO + T_W1 + T_W2 + T_WE) return;

  const float* src;
  unsigned short* dst;
  int within, ntc, ksc, N, Ksrc, lstride;
  if (gid < 4 * T_QKVO) {
    const int t = gid / T_QKVO;
    within = gid % T_QKVO;
    src = (t == 0 ? Wq : t == 1 ? Wk : t == 2 ? Wv : Wo);
    dst = ws + (t == 0 ? WQ_OFF : t == 1 ? WK_OFF : t == 2 ? WV_OFF : WO_OFF);
    ntc = 7; ksc = 4; N = 100; Ksrc = 100; lstride = 10000;
  } else if (gid < 4 * T_QKVO + T_W1) {
    within = gid - 4 * T_QKVO;
    src = W1; dst = ws + W1_OFF;
    ntc = 32; ksc = 4; N = 512; Ksrc = 100; lstride = 51200;
  } else if (gid < 4 * T_QKVO + T_W1 + T_W2) {
    within = gid - 4 * T_QKVO - T_W1;
    src = W2; dst = ws + W2_OFF;
    ntc = 7; ksc = 16; N = 100; Ksrc = 512; lstride = 51200;
  } else {
    within = gid - 4 * T_QKVO - T_W1 - T_W2;
    src = We; dst = ws + WE_OFF;
    ntc = 7; ksc = 3; N = 100; Ksrc = 72; lstride = 0;
  }
  const int lane = within & 63;
  int tmp = within >> 6;
  const int ks = tmp % ksc; tmp /= ksc;
  const int nt = tmp % ntc;
  const int lay = tmp / ntc;
  const int n = nt * 16 + (lane & 15);
  const int kb = ks * 32 + (lane >> 4) * 8;
  const float* sp = src + (size_t)lay * lstride + (size_t)n * Ksrc;
  unsigned short o[8];
#pragma unroll
  for (int j = 0; j < 8; ++j) {
    const int k = kb + j;
    float v = (n < N && k < Ksrc) ? sp[k] : 0.f;
    o[j] = f2bf(v);
  }
  uint4 pk = make_uint4((unsigned)o[0] | ((unsigned)o[1] << 16),
                        (unsigned)o[2] | ((unsigned)o[3] << 16),
                        (unsigned)o[4] | ((unsigned)o[5] << 16),
                        (unsigned)o[6] | ((unsigned)o[7] << 16));
  *reinterpret_cast<uint4*>(dst + (size_t)within * 8) = pk;
}

__global__ __launch_bounds__(NT, 3)
void geomap_mfma(const float* __restrict__ gx,
                 const float* __restrict__ be, const float* __restrict__ pe,
                 const float* __restrict__ bq, const float* __restrict__ bk,
                 const float* __restrict__ bv, const float* __restrict__ bo,
                 const float* __restrict__ g1, const float* __restrict__ bt1,
                 const float* __restrict__ b1, const float* __restrict__ b2,
                 const float* __restrict__ g2, const float* __restrict__ bt2,
                 const float* __restrict__ Wf, const float* __restrict__ bfc,
                 const unsigned short* __restrict__ ws,
                 float* __restrict__ gout) {
  // 51456 B -> 3 blocks/CU (3*51456 = 154368 <= 163840)
  __shared__ __align__(16) char smem[51456];
  unsigned short* sA = (unsigned short*)smem;            // [48][136]: X|V|ctx
  float* sXf = (float*)(smem + 13056);                   // [48][100] fp32 master
  unsigned short* sQ = (unsigned short*)(smem + 32256);  // [48][100] bf16
  unsigned short* sK = (unsigned short*)(smem + 41856);  // [48][100]
  float* scr = (float*)(smem + 32256);                   // [48][100] (alias C)
  unsigned short* sH = (unsigned short*)(smem + 32256);  // FFN bufs (alias C)

  const int tid = threadIdx.x;
  const int lane = tid & 63;
  const int wid = tid >> 6;
  const int l15 = lane & 15;
  const int quad = lane >> 4;
  const int blk = blockIdx.x;

  const int row_o = tid >> 2, ln_o = tid & 3;  // LN job (threads < 192)
  const int cnt_o = (ln_o == 0) ? 7 : 6;

  // ---- zero sA (pad cols stay 0 forever), then stage x as bf16 ----
  for (int i = tid; i < R * LDA / 2; i += NT) ((unsigned*)sA)[i] = 0u;
  __syncthreads();
  for (int i = tid; i < R * DIN / 2; i += NT) {
    const int row = i / 36, c = (i % 36) * 2;
    const float2 f2 = *(const float2*)(gx + ((size_t)blk * R + row) * DIN + c);
    ((unsigned*)sA)[row * (LDA / 2) + (c >> 1)] = pkbf(f2.x, f2.y);
  }
  __syncthreads();

  // ---- embedding via MFMA: sXf/sA = x @ We^T + be + pe ----
  {
    short8 xe[3][3];
#pragma unroll
    for (int mt = 0; mt < 3; ++mt)
#pragma unroll
      for (int ks = 0; ks < 3; ++ks)
        xe[mt][ks] = *(const short8*)(sA + (mt * 16 + l15) * LDA + ks * 32 + quad * 8);
    __syncthreads();  // all x-frags in regs before epilogue overwrites sA
    for (int nt = wid; nt < 7; nt += 4) {
      const unsigned short* wb = ws + WE_OFF + (size_t)(nt * 3) * 512 + (size_t)lane * 8;
      short8 w0 = *(const short8*)(wb);
      short8 w1 = *(const short8*)(wb + 512);
      short8 w2 = *(const short8*)(wb + 1024);
      const int n0 = nt * 16 + quad * 4;
      floatx4 a[3];
      __builtin_amdgcn_s_setprio(1);
#pragma unroll
      for (int mt = 0; mt < 3; ++mt) {
        a[mt] = floatx4{0.f, 0.f, 0.f, 0.f};
        a[mt] = MFMA_BF16(w0, xe[mt][0], a[mt], 0, 0, 0);
        a[mt] = MFMA_BF16(w1, xe[mt][1], a[mt], 0, 0, 0);
        a[mt] = MFMA_BF16(w2, xe[mt][2], a[mt], 0, 0, 0);
      }
      __builtin_amdgcn_s_setprio(0);
      if (n0 < D) {
        const floatx4 bev = *(const floatx4*)(be + n0);
#pragma unroll
        for (int mt = 0; mt < 3; ++mt) {
          const int row = mt * 16 + l15;
          const int s = row % 3;
          const floatx4 pev = *(const floatx4*)(pe + s * D + n0);
          const floatx4 o = a[mt] + bev + pev;
          *(floatx4*)(sXf + row * D + n0) = o;
          st_bf4(sA + row * LDA + n0, o);
        }
      }
    }
  }
  __syncthreads();

  for (int lay = 0; lay < L; ++lay) {
    // ---- QKV: 21 units; V lands in sA rows (X dead after xf capture) ----
    {
      short8 xf[3][4];
#pragma unroll
      for (int mt = 0; mt < 3; ++mt)
#pragma unroll
        for (int ks = 0; ks < 4; ++ks)
          xf[mt][ks] = *(const short8*)(sA + (mt * 16 + l15) * LDA + ks * 32 + quad * 8);
      __syncthreads();  // every wave has X frags; V may overwrite sA now
      const unsigned short* wbase[3] = {ws + WQ_OFF + lay * PL_QKVO,
                                        ws + WK_OFF + lay * PL_QKVO,
                                        ws + WV_OFF + lay * PL_QKVO};
      for (int u = wid; u < 21; u += 4) {
        const int mat = u / 7, nt = u % 7;
        short8 wf[4];
        ldwf4(wbase[mat] + (size_t)nt * 2048 + (size_t)lane * 8, wf);
        const int n0 = nt * 16 + quad * 4;
        floatx4 bias = {0.f, 0.f, 0.f, 0.f};
        const float* bsrc = (mat == 0 ? bq : mat == 1 ? bk : bv) + lay * D;
        if (n0 < D) bias = *(const floatx4*)(bsrc + n0);
        floatx4 a0 = bias, a1 = bias, a2 = bias;
        __builtin_amdgcn_s_setprio(1);
#pragma unroll
        for (int ks = 0; ks < 4; ++ks) {
          a0 = MFMA_BF16(wf[ks], xf[0][ks], a0, 0, 0, 0);
          a1 = MFMA_BF16(wf[ks], xf[1][ks], a1, 0, 0, 0);
          a2 = MFMA_BF16(wf[ks], xf[2][ks], a2, 0, 0, 0);
        }
        __builtin_amdgcn_s_setprio(0);
        if (n0 < D) {
          const floatx4 av[3] = {a0, a1, a2};
#pragma unroll
          for (int mt = 0; mt < 3; ++mt) {
            const int row = mt * 16 + l15;
            if (mat == 0) st_bf4(sQ + row * 100 + n0, av[mt]);
            else if (mat == 1) st_bf4(sK + row * 100 + n0, av[mt]);
            else st_bf4(sA + row * LDA + n0, av[mt]);  // V into sA
          }
        }
      }
    }
    __syncthreads();

    // ---- attention: 160 jobs = (e,h); V in sA, ctx written in-place ----
    if (tid < 160) {
      const int e = tid / 10, h = tid % 10;
      const unsigned short* Qe = sQ + e * 300;  // stride-100 rows -> flat 300
      const unsigned short* Ke = sK + e * 300;
      float Kv[3][10];
#pragma unroll
      for (int t = 0; t < 3; ++t) load10(Kv[t], Ke + h * 30 + t * 10);
      float p[3][3];
#pragma unroll
      for (int sq = 0; sq < 3; ++sq) {
        float q[10];
        load10(q, Qe + h * 30 + sq * 10);
        float sc[3];
#pragma unroll
        for (int t = 0; t < 3; ++t) {
          float s0 = 0.f;
#pragma unroll
          for (int j = 0; j < 10; ++j) s0 += q[j] * Kv[t][j];
          sc[t] = s0 * SCALE_L2E;  // exp2-base softmax (identical result)
        }
        const float m = fmaxf(sc[0], fmaxf(sc[1], sc[2]));
        float p0 = exp2f(sc[0] - m), p1 = exp2f(sc[1] - m), p2 = exp2f(sc[2] - m);
        const float inv = 1.f / (p0 + p1 + p2);
        p[sq][0] = p0 * inv; p[sq][1] = p1 * inv; p[sq][2] = p2 * inv;
      }
      float ctx[3][10];
#pragma unroll
      for (int sq = 0; sq < 3; ++sq)
#pragma unroll
        for (int j = 0; j < 10; ++j) ctx[sq][j] = 0.f;
#pragma unroll
      for (int t = 0; t < 3; ++t) {
        const int pv = h * 30 + t * 10;
        float vv[10];
        load10(vv, sA + (e * 3 + pv / 100) * LDA + (pv % 100));
#pragma unroll
        for (int sq = 0; sq < 3; ++sq)
#pragma unroll
          for (int j = 0; j < 10; ++j) ctx[sq][j] += p[sq][t] * vv[j];
      }
#pragma unroll
      for (int sq = 0; sq < 3; ++sq) {
        const int pq = h * 30 + sq * 10;
        unsigned* dp = (unsigned*)(sA + (e * 3 + pq / 100) * LDA + (pq % 100));
#pragma unroll
        for (int w = 0; w < 5; ++w)
          dp[w] = pkbf(ctx[sq][2 * w], ctx[sq][2 * w + 1]);
      }
    }
    __syncthreads();

    // ---- Wo -> scr (overwrites dead sQ/sK; residual added in LN1) ----
    {
      short8 cf[3][4];
#pragma unroll
      for (int mt = 0; mt < 3; ++mt)
#pragma unroll
        for (int ks = 0; ks < 4; ++ks)
          cf[mt][ks] = *(const short8*)(sA + (mt * 16 + l15) * LDA + ks * 32 + quad * 8);
      const unsigned short* wbase = ws + WO_OFF + lay * PL_QKVO;
      for (int u = wid; u < 7; u += 4) {
        short8 wf[4];
        ldwf4(wbase + (size_t)u * 2048 + (size_t)lane * 8, wf);
        const int n0 = u * 16 + quad * 4;
        floatx4 bias = {0.f, 0.f, 0.f, 0.f};
        if (n0 < D) bias = *(const floatx4*)(bo + lay * D + n0);
        floatx4 a0 = bias, a1 = bias, a2 = bias;
        __builtin_amdgcn_s_setprio(1);
#pragma unroll
        for (int ks = 0; ks < 4; ++ks) {
          a0 = MFMA_BF16(wf[ks], cf[0][ks], a0, 0, 0, 0);
          a1 = MFMA_BF16(wf[ks], cf[1][ks], a1, 0, 0, 0);
          a2 = MFMA_BF16(wf[ks], cf[2][ks], a2, 0, 0, 0);
        }
        __builtin_amdgcn_s_setprio(0);
        if (n0 < D) {
          const floatx4 av[3] = {a0, a1, a2};
#pragma unroll
          for (int mt = 0; mt < 3; ++mt)
            *(floatx4*)(scr + (mt * 16 + l15) * D + n0) = av[mt];
        }
      }
    }
    __syncthreads();
    if (tid < 192)
      ln_rows(sXf + row_o * D, scr + row_o * D, g1 + lay * D, bt1 + lay * D,
              sA + row_o * LDA, ln_o, cnt_o);
    __syncthreads();

    // ---- FFN ping-pong: 6 halves {96,96,96,96,96,32} hidden cols ----
    // Phase p: F1 builds half p (p<6) while F2 consumes half p-1 (p>0).
    // F1 global loads issued FIRST; F2 MFMA + interleaved F1 MFMA hide
    // their latency. Per-phase arch regs ~75 (ff/facc in AGPRs).
    {
      short8 ff[3][4];
#pragma unroll
      for (int mt = 0; mt < 3; ++mt)
#pragma unroll
        for (int ks = 0; ks < 4; ++ks)
          ff[mt][ks] = *(const short8*)(sA + (mt * 16 + l15) * LDA + ks * 32 + quad * 8);
      floatx4 facc[2][3];
      const int ntA = wid, ntB = wid + 4;
      const bool hasB2 = ntB < 7;
#pragma unroll
      for (int idx = 0; idx < 2; ++idx) {
        const int nt = idx == 0 ? ntA : ntB;
        const int n0 = nt * 16 + quad * 4;
        floatx4 bias = {0.f, 0.f, 0.f, 0.f};
        if (nt < 7 && n0 < D) bias = *(const floatx4*)(b2 + lay * D + n0);
#pragma unroll
        for (int mt = 0; mt < 3; ++mt) facc[idx][mt] = bias;
      }
      const unsigned short* w1b = ws + W1_OFF + (size_t)lay * PL_W1;
      const unsigned short* w2b = ws + W2_OFF + (size_t)lay * PL_W2;
      unsigned short* const bufA = sH;            // [48][96]
      unsigned short* const bufB = sH + 48 * 96;  // [48][96]

// One FFN1 hidden tile: 12 MFMA + ReLU + bf16 store into wbuf.
#define FFN1_UNIT(W0, W1_, W2_, W3, NTG, LC)                               \
  do {                                                                     \
    const floatx4 _bv =                                                    \
        *(const floatx4*)(b1 + lay * FF + (NTG) * 16 + quad * 4);          \
    floatx4 _a0 = _bv, _a1 = _bv, _a2 = _bv;                               \
    __builtin_amdgcn_s_setprio(1);                                         \
    _a0 = MFMA_BF16(W0, ff[0][0], _a0, 0, 0, 0);                           \
    _a1 = MFMA_BF16(W0, ff[1][0], _a1, 0, 0, 0);                           \
    _a2 = MFMA_BF16(W0, ff[2][0], _a2, 0, 0, 0);                           \
    _a0 = MFMA_BF16(W1_, ff[0][1], _a0, 0, 0, 0);                          \
    _a1 = MFMA_BF16(W1_, ff[1][1], _a1, 0, 0, 0);                          \
    _a2 = MFMA_BF16(W1_, ff[2][1], _a2, 0, 0, 0);                          \
    _a0 = MFMA_BF16(W2_, ff[0][2], _a0, 0, 0, 0);                          \
    _a1 = MFMA_BF16(W2_, ff[1][2], _a1, 0, 0, 0);                          \
    _a2 = MFMA_BF16(W2_, ff[2][2], _a2, 0, 0, 0);                          \
    _a0 = MFMA_BF16(W3, ff[0][3], _a0, 0, 0, 0);                           \
    _a1 = MFMA_BF16(W3, ff[1][3], _a1, 0, 0, 0);                           \
    _a2 = MFMA_BF16(W3, ff[2][3], _a2, 0, 0, 0);                           \
    __builtin_amdgcn_s_setprio(0);                                         \
    const int _nc = (LC) + quad * 4;                                       \
    floatx4 _r;                                                            \
    _r.x = fmaxf(_a0.x, 0.f); _r.y = fmaxf(_a0.y, 0.f);                    \
    _r.z = fmaxf(_a0.z, 0.f); _r.w = fmaxf(_a0.w, 0.f);                    \
    st_bf4(wbuf + (l15) * 96 + _nc, _r);                                   \
    _r.x = fmaxf(_a1.x, 0.f); _r.y = fmaxf(_a1.y, 0.f);                    \
    _r.z = fmaxf(_a1.z, 0.f); _r.w = fmaxf(_a1.w, 0.f);                    \
    st_bf4(wbuf + (16 + l15) * 96 + _nc, _r);                              \
    _r.x = fmaxf(_a2.x, 0.f); _r.y = fmaxf(_a2.y, 0.f);                    \
    _r.z = fmaxf(_a2.z, 0.f); _r.w = fmaxf(_a2.w, 0.f);                    \
    st_bf4(wbuf + (32 + l15) * 96 + _nc, _r);                              \
  } while (0)

// One FFN2 K-step: 3 hf reads + up to 6 MFMA into facc.
#define FFN2_STEP(WA, WB, KSL)                                             \
  do {                                                                     \
    const int _ko = (KSL) * 32 + quad * 8;                                 \
    short8 _h0 = *(const short8*)(rbuf + (l15) * 96 + _ko);                \
    short8 _h1 = *(const short8*)(rbuf + (16 + l15) * 96 + _ko);           \
    short8 _h2 = *(const short8*)(rbuf + (32 + l15) * 96 + _ko);           \
    __builtin_amdgcn_s_setprio(1);                                         \
    facc[0][0] = MFMA_BF16(WA, _h0, facc[0][0], 0, 0, 0);                  \
    facc[0][1] = MFMA_BF16(WA, _h1, facc[0][1], 0, 0, 0);                  \
    facc[0][2] = MFMA_BF16(WA, _h2, facc[0][2], 0, 0, 0);                  \
    if (hasB2) {                                                           \
      facc[1][0] = MFMA_BF16(WB, _h0, facc[1][0], 0, 0, 0);                \
      facc[1][1] = MFMA_BF16(WB, _h1, facc[1][1], 0, 0, 0);                \
      facc[1][2] = MFMA_BF16(WB, _h2, facc[1][2], 0, 0, 0);                \
    }                                                                      \
    __builtin_amdgcn_s_setprio(0);                                         \
  } while (0)

#pragma unroll
      for (int p = 0; p < 7; ++p) {
        unsigned short* const wbuf = (p & 1) ? bufB : bufA;
        const unsigned short* const rbuf = (p & 1) ? bufA : bufB;
        // F1 weight issue (half p). Tail half (p==5) has 2 units: waves
        // 2,3 load clamped addresses (valid data, compute/store guarded).
        const int la = (p == 5) ? (wid & 1) : wid;
        const bool aOK = (p != 5) || (wid < 2);
        const bool bOn = (p < 6) && (p != 5) && (wid < 2);
        short8 fa0, fa1, fa2, fa3, fb0, fb1, fb2, fb3;
        if (p < 6) {
          const unsigned short* pa =
              w1b + (size_t)(p * 6 + la) * 2048 + (size_t)lane * 8;
          fa0 = *(const short8*)(pa);
          fa1 = *(const short8*)(pa + 512);
          fa2 = *(const short8*)(pa + 1024);
          fa3 = *(const short8*)(pa + 1536);
          if (bOn) {
            const unsigned short* pb =
                w1b + (size_t)(p * 6 + wid + 4) * 2048 + (size_t)lane * 8;
            fb0 = *(const short8*)(pb);
            fb1 = *(const short8*)(pb + 512);
            fb2 = *(const short8*)(pb + 1024);
            fb3 = *(const short8*)(pb + 1536);
          }
        }
        if (p == 0) {
          FFN1_UNIT(fa0, fa1, fa2, fa3, wid, wid * 16);
          if (bOn)
            FFN1_UNIT(fb0, fb1, fb2, fb3, wid + 4, (wid + 4) * 16);
        } else {
          const int q = p - 1;
          // ksl0 weights issued before F1-A compute (latency hidden)
          short8 wA0 = *(const short8*)(w2b + (size_t)(ntA * 16 + q * 3) * 512 +
                                        (size_t)lane * 8);
          short8 wB0 = wA0;
          if (hasB2)
            wB0 = *(const short8*)(w2b + (size_t)(ntB * 16 + q * 3) * 512 +
                                   (size_t)lane * 8);
          if (p < 6 && aOK)
            FFN1_UNIT(fa0, fa1, fa2, fa3, p * 6 + la, la * 16);
          if (q < 5) {
            short8 wA1 = *(const short8*)(w2b +
                                          (size_t)(ntA * 16 + q * 3 + 1) * 512 +
                                          (size_t)lane * 8);
            short8 wB1 = wA1;
            if (hasB2)
              wB1 = *(const short8*)(w2b +
                                     (size_t)(ntB * 16 + q * 3 + 1) * 512 +
                                     (size_t)lane * 8);
            FFN2_STEP(wA0, wB0, 0);
            if (bOn)
              FFN1_UNIT(fb0, fb1, fb2, fb3, p * 6 + wid + 4, (wid + 4) * 16);
            short8 wA2 = *(const short8*)(w2b +
                                          (size_t)(ntA * 16 + q * 3 + 2) * 512 +
                                          (size_t)lane * 8);
            short8 wB2 = wA2;
            if (hasB2)
              wB2 = *(const short8*)(w2b +
                                     (size_t)(ntB * 16 + q * 3 + 2) * 512 +
                                     (size_t)lane * 8);
            FFN2_STEP(wA1, wB1, 1);
            FFN2_STEP(wA2, wB2, 2);
          } else {
            FFN2_STEP(wA0, wB0, 0);  // tail half: single K-step (gks=15)
          }
        }
        __syncthreads();
      }
#undef FFN1_UNIT
#undef FFN2_STEP
      // FFN2 epilogue -> scr (overwrites dead FFN bufs)
#pragma unroll
      for (int idx = 0; idx < 2; ++idx) {
        const int nt = idx == 0 ? ntA : ntB;
        const int n0 = nt * 16 + quad * 4;
        if (nt < 7 && n0 < D) {
#pragma unroll
          for (int mt = 0; mt < 3; ++mt)
            *(floatx4*)(scr + (mt * 16 + l15) * D + n0) = facc[idx][mt];
        }
      }
    }
    __syncthreads();
    if (tid < 192)
      ln_rows(sXf + row_o * D, scr + row_o * D, g2 + lay * D, bt2 + lay * D,
              sA + row_o * LDA, ln_o, cnt_o);
    __syncthreads();
  }

  // ---- classifier (fp32 VALU, exact): reads sXf master directly ----
  if (tid < 160) {
    const int c = tid % 40, eg = tid / 40;
    float acc[4];
#pragma unroll
    for (int i = 0; i < 4; ++i) acc[i] = bfc[c];
    const floatx4* wr = (const floatx4*)(Wf + c * 300);
    for (int kq = 0; kq < 75; ++kq) {
      const floatx4 w4 = wr[kq];
#pragma unroll
      for (int i = 0; i < 4; ++i) {
        const floatx4 x4 = *(const floatx4*)(sXf + (eg * 4 + i) * 300 + kq * 4);
        acc[i] += w4.x * x4.x + w4.y * x4.y + w4.z * x4.z + w4.w * x4.w;
      }
    }
#pragma unroll
    for (int i = 0; i < 4; ++i)
      gout[((size_t)blk * NB + eg * 4 + i) * CLS + c] = acc[i];
  }
}

extern "C" void kernel_launch(void* const* d_in, const int* in_sizes, int n_in,
                              void* d_out, int out_size, void* d_ws,
                              size_t ws_size, hipStream_t stream) {
  const float* x   = (const float*)d_in[0];
  const float* We  = (const float*)d_in[3];
  const float* be  = (const float*)d_in[4];
  const float* pe  = (const float*)d_in[5];
  const float* Wq  = (const float*)d_in[6];
  const float* bq  = (const float*)d_in[7];
  const float* Wk  = (const float*)d_in[8];
  const float* bk  = (const float*)d_in[9];
  const float* Wv  = (const float*)d_in[10];
  const float* bv  = (const float*)d_in[11];
  const float* Wo  = (const float*)d_in[12];
  const float* bo  = (const float*)d_in[13];
  const float* g1  = (const float*)d_in[14];
  const float* bt1 = (const float*)d_in[15];
  const float* W1  = (const float*)d_in[16];
  const float* b1  = (const float*)d_in[17];
  const float* W2  = (const float*)d_in[18];
  const float* b2  = (const float*)d_in[19];
  const float* g2  = (const float*)d_in[20];
  const float* bt2 = (const float*)d_in[21];
  const float* Wf  = (const float*)d_in[22];
  const float* bf  = (const float*)d_in[23];
  float* out = (float*)d_out;
  unsigned short* ws = (unsigned short*)d_ws;

  prep_weights<<<710, 256, 0, stream>>>(Wq, Wk, Wv, Wo, W1, W2, We, ws);

  const int B = in_sizes[0] / (S * DIN);
  const int blocks = B / NB;  // 4096
  geomap_mfma<<<blocks, NT, 0, stream>>>(x, be, pe, bq, bk, bv, bo,
                                         g1, bt1, b1, b2, g2, bt2, Wf, bf,
                                         ws, out);
}

// Round 12
// 1289.598 us; speedup vs baseline: 1.0894x; 1.0894x over previous
//
#include <hip/hip_runtime.h>
#include <hip/hip_bf16.h>

// GeoMapNet fused forward, MFMA bf16, LDS-resident fp32 master (R18).
// R18 = R14 (1201 us) + FFN ping-pong v2. R17's ping-pong regressed
// (1405) from two measured mechanisms: (1) stride-96 buffers -> dword
// stride 48 = 16 mod 32 -> ~8-way bank conflicts (counter +81%);
// (2) conditionally-loaded named prefetch vars in unrolled tail phases ->
// mild scratch (WRITE 96->137 MB) + fetch amplification (126->264 MB).
// v2 fixes both: 8 halves x 64 cols -> exactly 1 F1 unit/wave/phase
// (uniform control flow, zero conditional liveness); buffers [48][72]
// (144 B rows: 16B-aligned, dword stride 4 mod 32 -> uniform 2-way,
// conflict-free); steady phases rolled (#pragma unroll 1, small code).
// Phase: F1 loads -> W2 ksl0 loads -> F2(0) -> W2 ksl1 loads -> F1
// (12 MFMA hide latencies) -> F2(1) -> barrier. 9 FFN barriers vs 6.

typedef __attribute__((ext_vector_type(8))) short short8;   // 8 bf16
typedef __attribute__((ext_vector_type(4))) float floatx4;  // MFMA C/D

namespace {
constexpr int S = 3, DIN = 72, D = 100, FF = 512, L = 8, CLS = 40;
constexpr int NB = 16, R = 48, NT = 256;
constexpr int LDA = 136;   // sA row stride (shorts): 16B-aligned, bank-rotated
constexpr int LDF = 72;    // FFN buf row stride (shorts): 144 B, 2-way banks
// DH^-0.5 * log2(e): softmax via exp2 (identical result, saves a mul/exp)
constexpr float SCALE_L2E = 0.45622024f;

// d_ws element offsets (bf16). Fragment block = 64 lanes x 8 bf16.
constexpr int PL_QKVO = 7 * 4 * 512;                 // per layer
constexpr int WQ_OFF = 0;
constexpr int WK_OFF = WQ_OFF + L * PL_QKVO;
constexpr int WV_OFF = WK_OFF + L * PL_QKVO;
constexpr int WO_OFF = WV_OFF + L * PL_QKVO;
constexpr int PL_W1 = 32 * 4 * 512;
constexpr int W1_OFF = WO_OFF + L * PL_QKVO;
constexpr int PL_W2 = 7 * 16 * 512;
constexpr int W2_OFF = W1_OFF + L * PL_W1;
constexpr int WE_OFF = W2_OFF + L * PL_W2;           // 7 nt x 3 ks
}  // namespace

#define MFMA_BF16 __builtin_amdgcn_mfma_f32_16x16x32_bf16

__device__ __forceinline__ unsigned short f2bf(float f) {  // RTNE (prep only)
  unsigned int u = __float_as_uint(f);
  u = u + 0x7fffu + ((u >> 16) & 1u);
  return (unsigned short)(u >> 16);
}

__device__ __forceinline__ unsigned pkbf(float a, float b) {  // packed cvt
  __hip_bfloat162 h = __float22bfloat162_rn(make_float2(a, b));
  return *reinterpret_cast<unsigned*>(&h);
}

__device__ __forceinline__ void st_bf4(unsigned short* p, floatx4 v) {
  *reinterpret_cast<uint2*>(p) = make_uint2(pkbf(v.x, v.y), pkbf(v.z, v.w));
}

__device__ __forceinline__ void load10(float* o, const unsigned short* p) {
  const unsigned* u = (const unsigned*)p;  // 4B-aligned (even col)
#pragma unroll
  for (int w = 0; w < 5; ++w) {
    unsigned x = u[w];
    o[2 * w] = __uint_as_float(x << 16);
    o[2 * w + 1] = __uint_as_float(x & 0xffff0000u);
  }
}

__device__ __forceinline__ void ldwf4(const unsigned short* base, short8* o) {
#pragma unroll
  for (int ks = 0; ks < 4; ++ks) o[ks] = *(const short8*)(base + ks * 512);
}

// LayerNorm over 48 rows of 100; 4 lanes/row (192 threads), vectorized.
__device__ __forceinline__ void ln_rows(float* xrow, const float* srow,
                                        const float* __restrict__ g,
                                        const float* __restrict__ b,
                                        unsigned short* sArow, int ln,
                                        int cnt) {
  floatx4 v[7];
  float sum = 0.f;
#pragma unroll
  for (int i = 0; i < 7; ++i)
    if (i < cnt) {
      const int col = i * 16 + ln * 4;
      floatx4 t = *(const floatx4*)(xrow + col) + *(const floatx4*)(srow + col);
      v[i] = t;
      sum += t.x + t.y + t.z + t.w;
    }
  sum += __shfl_xor(sum, 1, 4);
  sum += __shfl_xor(sum, 2, 4);
  const float mean = sum * 0.01f;
  float var = 0.f;
#pragma unroll
  for (int i = 0; i < 7; ++i)
    if (i < cnt) {
      floatx4 d = v[i] - mean;
      var += d.x * d.x + d.y * d.y + d.z * d.z + d.w * d.w;
    }
  var += __shfl_xor(var, 1, 4);
  var += __shfl_xor(var, 2, 4);
  const float rstd = rsqrtf(var * 0.01f + 1e-5f);
#pragma unroll
  for (int i = 0; i < 7; ++i)
    if (i < cnt) {
      const int col = i * 16 + ln * 4;
      floatx4 o = (v[i] - mean) * rstd * *(const floatx4*)(g + col) +
                  *(const floatx4*)(b + col);
      *(floatx4*)(xrow + col) = o;
      st_bf4(sArow + col, o);
    }
}

// ------------- weight pre-pack: fp32 row-major -> bf16 fragment blocks -----
__global__ void prep_weights(const float* __restrict__ Wq, const float* __restrict__ Wk,
                             const float* __restrict__ Wv, const float* __restrict__ Wo,
                             const float* __restrict__ W1, const float* __restrict__ W2,
                             const float* __restrict__ We,
                             unsigned short* __restrict__ ws) {
  const int gid = blockIdx.x * 256 + threadIdx.x;
  constexpr int T_QKVO = 8 * 7 * 4 * 64;  // 14336
  constexpr int T_W1 = 8 * 32 * 4 * 64;   // 65536
  constexpr int T_W2 = 8 * 7 * 16 * 64;   // 57344
  constexpr int T_WE = 7 * 3 * 64;        // 1344
  if (gid >= 4 * T_QKVO + T_W1 + T_W2 + T_WE) return;

  const float* src;
  unsigned short* dst;
  int within, ntc, ksc, N, Ksrc, lstride;
  if (gid < 4 * T_QKVO) {
    const int t = gid / T_QKVO;
    within = gid % T_QKVO;
    src = (t == 0 ? Wq : t == 1 ? Wk : t == 2 ? Wv : Wo);
    dst = ws + (t == 0 ? WQ_OFF : t == 1 ? WK_OFF : t == 2 ? WV_OFF : WO_OFF);
    ntc = 7; ksc = 4; N = 100; Ksrc = 100; lstride = 10000;
  } else if (gid < 4 * T_QKVO + T_W1) {
    within = gid - 4 * T_QKVO;
    src = W1; dst = ws + W1_OFF;
    ntc = 32; ksc = 4; N = 512; Ksrc = 100; lstride = 51200;
  } else if (gid < 4 * T_QKVO + T_W1 + T_W2) {
    within = gid - 4 * T_QKVO - T_W1;
    src = W2; dst = ws + W2_OFF;
    ntc = 7; ksc = 16; N = 100; Ksrc = 512; lstride = 51200;
  } else {
    within = gid - 4 * T_QKVO - T_W1 - T_W2;
    src = We; dst = ws + WE_OFF;
    ntc = 7; ksc = 3; N = 100; Ksrc = 72; lstride = 0;
  }
  const int lane = within & 63;
  int tmp = within >> 6;
  const int ks = tmp % ksc; tmp /= ksc;
  const int nt = tmp % ntc;
  const int lay = tmp / ntc;
  const int n = nt * 16 + (lane & 15);
  const int kb = ks * 32 + (lane >> 4) * 8;
  const float* sp = src + (size_t)lay * lstride + (size_t)n * Ksrc;
  unsigned short o[8];
#pragma unroll
  for (int j = 0; j < 8; ++j) {
    const int k = kb + j;
    float v = (n < N && k < Ksrc) ? sp[k] : 0.f;
    o[j] = f2bf(v);
  }
  uint4 pk = make_uint4((unsigned)o[0] | ((unsigned)o[1] << 16),
                        (unsigned)o[2] | ((unsigned)o[3] << 16),
                        (unsigned)o[4] | ((unsigned)o[5] << 16),
                        (unsigned)o[6] | ((unsigned)o[7] << 16));
  *reinterpret_cast<uint4*>(dst + (size_t)within * 8) = pk;
}

__global__ __launch_bounds__(NT, 3)
void geomap_mfma(const float* __restrict__ gx,
                 const float* __restrict__ be, const float* __restrict__ pe,
                 const float* __restrict__ bq, const float* __restrict__ bk,
                 const float* __restrict__ bv, const float* __restrict__ bo,
                 const float* __restrict__ g1, const float* __restrict__ bt1,
                 const float* __restrict__ b1, const float* __restrict__ b2,
                 const float* __restrict__ g2, const float* __restrict__ bt2,
                 const float* __restrict__ Wf, const float* __restrict__ bfc,
                 const unsigned short* __restrict__ ws,
                 float* __restrict__ gout) {
  // 51456 B -> 3 blocks/CU (3*51456 = 154368 <= 163840)
  __shared__ __align__(16) char smem[51456];
  unsigned short* sA = (unsigned short*)smem;            // [48][136]: X|V|ctx
  float* sXf = (float*)(smem + 13056);                   // [48][100] fp32 master
  unsigned short* sQ = (unsigned short*)(smem + 32256);  // [48][100] bf16
  unsigned short* sK = (unsigned short*)(smem + 41856);  // [48][100]
  float* scr = (float*)(smem + 32256);                   // [48][100] (alias C)
  unsigned short* sH = (unsigned short*)(smem + 32256);  // FFN bufs (alias C)

  const int tid = threadIdx.x;
  const int lane = tid & 63;
  const int wid = tid >> 6;
  const int l15 = lane & 15;
  const int quad = lane >> 4;
  const int blk = blockIdx.x;

  const int row_o = tid >> 2, ln_o = tid & 3;  // LN job (threads < 192)
  const int cnt_o = (ln_o == 0) ? 7 : 6;

  // ---- zero sA (pad cols stay 0 forever), then stage x as bf16 ----
  for (int i = tid; i < R * LDA / 2; i += NT) ((unsigned*)sA)[i] = 0u;
  __syncthreads();
  for (int i = tid; i < R * DIN / 2; i += NT) {
    const int row = i / 36, c = (i % 36) * 2;
    const float2 f2 = *(const float2*)(gx + ((size_t)blk * R + row) * DIN + c);
    ((unsigned*)sA)[row * (LDA / 2) + (c >> 1)] = pkbf(f2.x, f2.y);
  }
  __syncthreads();

  // ---- embedding via MFMA: sXf/sA = x @ We^T + be + pe ----
  {
    short8 xe[3][3];
#pragma unroll
    for (int mt = 0; mt < 3; ++mt)
#pragma unroll
      for (int ks = 0; ks < 3; ++ks)
        xe[mt][ks] = *(const short8*)(sA + (mt * 16 + l15) * LDA + ks * 32 + quad * 8);
    __syncthreads();  // all x-frags in regs before epilogue overwrites sA
    for (int nt = wid; nt < 7; nt += 4) {
      const unsigned short* wb = ws + WE_OFF + (size_t)(nt * 3) * 512 + (size_t)lane * 8;
      short8 w0 = *(const short8*)(wb);
      short8 w1 = *(const short8*)(wb + 512);
      short8 w2 = *(const short8*)(wb + 1024);
      const int n0 = nt * 16 + quad * 4;
      floatx4 a[3];
      __builtin_amdgcn_s_setprio(1);
#pragma unroll
      for (int mt = 0; mt < 3; ++mt) {
        a[mt] = floatx4{0.f, 0.f, 0.f, 0.f};
        a[mt] = MFMA_BF16(w0, xe[mt][0], a[mt], 0, 0, 0);
        a[mt] = MFMA_BF16(w1, xe[mt][1], a[mt], 0, 0, 0);
        a[mt] = MFMA_BF16(w2, xe[mt][2], a[mt], 0, 0, 0);
      }
      __builtin_amdgcn_s_setprio(0);
      if (n0 < D) {
        const floatx4 bev = *(const floatx4*)(be + n0);
#pragma unroll
        for (int mt = 0; mt < 3; ++mt) {
          const int row = mt * 16 + l15;
          const int s = row % 3;
          const floatx4 pev = *(const floatx4*)(pe + s * D + n0);
          const floatx4 o = a[mt] + bev + pev;
          *(floatx4*)(sXf + row * D + n0) = o;
          st_bf4(sA + row * LDA + n0, o);
        }
      }
    }
  }
  __syncthreads();

  for (int lay = 0; lay < L; ++lay) {
    // ---- QKV: 21 units; V lands in sA rows (X dead after xf capture) ----
    {
      short8 xf[3][4];
#pragma unroll
      for (int mt = 0; mt < 3; ++mt)
#pragma unroll
        for (int ks = 0; ks < 4; ++ks)
          xf[mt][ks] = *(const short8*)(sA + (mt * 16 + l15) * LDA + ks * 32 + quad * 8);
      __syncthreads();  // every wave has X frags; V may overwrite sA now
      const unsigned short* wbase[3] = {ws + WQ_OFF + lay * PL_QKVO,
                                        ws + WK_OFF + lay * PL_QKVO,
                                        ws + WV_OFF + lay * PL_QKVO};
      for (int u = wid; u < 21; u += 4) {
        const int mat = u / 7, nt = u % 7;
        short8 wf[4];
        ldwf4(wbase[mat] + (size_t)nt * 2048 + (size_t)lane * 8, wf);
        const int n0 = nt * 16 + quad * 4;
        floatx4 bias = {0.f, 0.f, 0.f, 0.f};
        const float* bsrc = (mat == 0 ? bq : mat == 1 ? bk : bv) + lay * D;
        if (n0 < D) bias = *(const floatx4*)(bsrc + n0);
        floatx4 a0 = bias, a1 = bias, a2 = bias;
        __builtin_amdgcn_s_setprio(1);
#pragma unroll
        for (int ks = 0; ks < 4; ++ks) {
          a0 = MFMA_BF16(wf[ks], xf[0][ks], a0, 0, 0, 0);
          a1 = MFMA_BF16(wf[ks], xf[1][ks], a1, 0, 0, 0);
          a2 = MFMA_BF16(wf[ks], xf[2][ks], a2, 0, 0, 0);
        }
        __builtin_amdgcn_s_setprio(0);
        if (n0 < D) {
          const floatx4 av[3] = {a0, a1, a2};
#pragma unroll
          for (int mt = 0; mt < 3; ++mt) {
            const int row = mt * 16 + l15;
            if (mat == 0) st_bf4(sQ + row * 100 + n0, av[mt]);
            else if (mat == 1) st_bf4(sK + row * 100 + n0, av[mt]);
            else st_bf4(sA + row * LDA + n0, av[mt]);  // V into sA
          }
        }
      }
    }
    __syncthreads();

    // ---- attention: 160 jobs = (e,h); V in sA, ctx written in-place ----
    if (tid < 160) {
      const int e = tid / 10, h = tid % 10;
      const unsigned short* Qe = sQ + e * 300;  // stride-100 rows -> flat 300
      const unsigned short* Ke = sK + e * 300;
      float Kv[3][10];
#pragma unroll
      for (int t = 0; t < 3; ++t) load10(Kv[t], Ke + h * 30 + t * 10);
      float p[3][3];
#pragma unroll
      for (int sq = 0; sq < 3; ++sq) {
        float q[10];
        load10(q, Qe + h * 30 + sq * 10);
        float sc[3];
#pragma unroll
        for (int t = 0; t < 3; ++t) {
          float s0 = 0.f;
#pragma unroll
          for (int j = 0; j < 10; ++j) s0 += q[j] * Kv[t][j];
          sc[t] = s0 * SCALE_L2E;  // exp2-base softmax (identical result)
        }
        const float m = fmaxf(sc[0], fmaxf(sc[1], sc[2]));
        float p0 = exp2f(sc[0] - m), p1 = exp2f(sc[1] - m), p2 = exp2f(sc[2] - m);
        const float inv = 1.f / (p0 + p1 + p2);
        p[sq][0] = p0 * inv; p[sq][1] = p1 * inv; p[sq][2] = p2 * inv;
      }
      float ctx[3][10];
#pragma unroll
      for (int sq = 0; sq < 3; ++sq)
#pragma unroll
        for (int j = 0; j < 10; ++j) ctx[sq][j] = 0.f;
#pragma unroll
      for (int t = 0; t < 3; ++t) {
        const int pv = h * 30 + t * 10;
        float vv[10];
        load10(vv, sA + (e * 3 + pv / 100) * LDA + (pv % 100));
#pragma unroll
        for (int sq = 0; sq < 3; ++sq)
#pragma unroll
          for (int j = 0; j < 10; ++j) ctx[sq][j] += p[sq][t] * vv[j];
      }
#pragma unroll
      for (int sq = 0; sq < 3; ++sq) {
        const int pq = h * 30 + sq * 10;
        unsigned* dp = (unsigned*)(sA + (e * 3 + pq / 100) * LDA + (pq % 100));
#pragma unroll
        for (int w = 0; w < 5; ++w)
          dp[w] = pkbf(ctx[sq][2 * w], ctx[sq][2 * w + 1]);
      }
    }
    __syncthreads();

    // ---- Wo -> scr (overwrites dead sQ/sK; residual added in LN1) ----
    {
      short8 cf[3][4];
#pragma unroll
      for (int mt = 0; mt < 3; ++mt)
#pragma unroll
        for (int ks = 0; ks < 4; ++ks)
          cf[mt][ks] = *(const short8*)(sA + (mt * 16 + l15) * LDA + ks * 32 + quad * 8);
      const unsigned short* wbase = ws + WO_OFF + lay * PL_QKVO;
      for (int u = wid; u < 7; u += 4) {
        short8 wf[4];
        ldwf4(wbase + (size_t)u * 2048 + (size_t)lane * 8, wf);
        const int n0 = u * 16 + quad * 4;
        floatx4 bias = {0.f, 0.f, 0.f, 0.f};
        if (n0 < D) bias = *(const floatx4*)(bo + lay * D + n0);
        floatx4 a0 = bias, a1 = bias, a2 = bias;
        __builtin_amdgcn_s_setprio(1);
#pragma unroll
        for (int ks = 0; ks < 4; ++ks) {
          a0 = MFMA_BF16(wf[ks], cf[0][ks], a0, 0, 0, 0);
          a1 = MFMA_BF16(wf[ks], cf[1][ks], a1, 0, 0, 0);
          a2 = MFMA_BF16(wf[ks], cf[2][ks], a2, 0, 0, 0);
        }
        __builtin_amdgcn_s_setprio(0);
        if (n0 < D) {
          const floatx4 av[3] = {a0, a1, a2};
#pragma unroll
          for (int mt = 0; mt < 3; ++mt)
            *(floatx4*)(scr + (mt * 16 + l15) * D + n0) = av[mt];
        }
      }
    }
    __syncthreads();
    if (tid < 192)
      ln_rows(sXf + row_o * D, scr + row_o * D, g1 + lay * D, bt1 + lay * D,
              sA + row_o * LDA, ln_o, cnt_o);
    __syncthreads();

    // ---- FFN ping-pong v2: 8 halves x 64 cols, 1 F1 unit/wave/phase ----
    {
      short8 ff[3][4];
#pragma unroll
      for (int mt = 0; mt < 3; ++mt)
#pragma unroll
        for (int ks = 0; ks < 4; ++ks)
          ff[mt][ks] = *(const short8*)(sA + (mt * 16 + l15) * LDA + ks * 32 + quad * 8);
      floatx4 facc[2][3];
      const int ntA = wid, ntB = wid + 4;
      const bool hasB2 = ntB < 7;
#pragma unroll
      for (int idx = 0; idx < 2; ++idx) {
        const int nt = idx == 0 ? ntA : ntB;
        const int n0 = nt * 16 + quad * 4;
        floatx4 bias = {0.f, 0.f, 0.f, 0.f};
        if (nt < 7 && n0 < D) bias = *(const floatx4*)(b2 + lay * D + n0);
#pragma unroll
        for (int mt = 0; mt < 3; ++mt) facc[idx][mt] = bias;
      }
      const unsigned short* w1b = ws + W1_OFF + (size_t)lay * PL_W1;
      const unsigned short* w2b = ws + W2_OFF + (size_t)lay * PL_W2;
      unsigned short* const bufA = sH;             // [48][72]
      unsigned short* const bufB = sH + 48 * LDF;  // [48][72]

      // One F1 unit (this wave's 16 cols of the 64-wide half).
      auto f1_unit = [&](short8 u0, short8 u1, short8 u2, short8 u3, int gu,
                         unsigned short* wbuf) {
        const floatx4 b1v =
            *(const floatx4*)(b1 + lay * FF + gu * 16 + quad * 4);
        floatx4 a0 = b1v, a1 = b1v, a2 = b1v;
        __builtin_amdgcn_s_setprio(1);
        a0 = MFMA_BF16(u0, ff[0][0], a0, 0, 0, 0);
        a1 = MFMA_BF16(u0, ff[1][0], a1, 0, 0, 0);
        a2 = MFMA_BF16(u0, ff[2][0], a2, 0, 0, 0);
        a0 = MFMA_BF16(u1, ff[0][1], a0, 0, 0, 0);
        a1 = MFMA_BF16(u1, ff[1][1], a1, 0, 0, 0);
        a2 = MFMA_BF16(u1, ff[2][1], a2, 0, 0, 0);
        a0 = MFMA_BF16(u2, ff[0][2], a0, 0, 0, 0);
        a1 = MFMA_BF16(u2, ff[1][2], a1, 0, 0, 0);
        a2 = MFMA_BF16(u2, ff[2][2], a2, 0, 0, 0);
        a0 = MFMA_BF16(u3, ff[0][3], a0, 0, 0, 0);
        a1 = MFMA_BF16(u3, ff[1][3], a1, 0, 0, 0);
        a2 = MFMA_BF16(u3, ff[2][3], a2, 0, 0, 0);
        __builtin_amdgcn_s_setprio(0);
        const int nc = wid * 16 + quad * 4;
        floatx4 r;
        r.x = fmaxf(a0.x, 0.f); r.y = fmaxf(a0.y, 0.f);
        r.z = fmaxf(a0.z, 0.f); r.w = fmaxf(a0.w, 0.f);
        st_bf4(wbuf + l15 * LDF + nc, r);
        r.x = fmaxf(a1.x, 0.f); r.y = fmaxf(a1.y, 0.f);
        r.z = fmaxf(a1.z, 0.f); r.w = fmaxf(a1.w, 0.f);
        st_bf4(wbuf + (16 + l15) * LDF + nc, r);
        r.x = fmaxf(a2.x, 0.f); r.y = fmaxf(a2.y, 0.f);
        r.z = fmaxf(a2.z, 0.f); r.w = fmaxf(a2.w, 0.f);
        st_bf4(wbuf + (32 + l15) * LDF + nc, r);
      };
      // One F2 K-step (local ksl 0/1 within a half).
      auto f2_step = [&](short8 wA, short8 wB, const unsigned short* rbuf,
                         int kl) {
        const int ko = kl * 32 + quad * 8;
        short8 h0 = *(const short8*)(rbuf + l15 * LDF + ko);
        short8 h1 = *(const short8*)(rbuf + (16 + l15) * LDF + ko);
        short8 h2 = *(const short8*)(rbuf + (32 + l15) * LDF + ko);
        __builtin_amdgcn_s_setprio(1);
        facc[0][0] = MFMA_BF16(wA, h0, facc[0][0], 0, 0, 0);
        facc[0][1] = MFMA_BF16(wA, h1, facc[0][1], 0, 0, 0);
        facc[0][2] = MFMA_BF16(wA, h2, facc[0][2], 0, 0, 0);
        if (hasB2) {
          facc[1][0] = MFMA_BF16(wB, h0, facc[1][0], 0, 0, 0);
          facc[1][1] = MFMA_BF16(wB, h1, facc[1][1], 0, 0, 0);
          facc[1][2] = MFMA_BF16(wB, h2, facc[1][2], 0, 0, 0);
        }
        __builtin_amdgcn_s_setprio(0);
      };

      // prologue: F1 half 0 (unit = wid) -> bufA
      {
        const unsigned short* pa = w1b + (size_t)wid * 2048 + (size_t)lane * 8;
        short8 u0 = *(const short8*)(pa);
        short8 u1 = *(const short8*)(pa + 512);
        short8 u2 = *(const short8*)(pa + 1024);
        short8 u3 = *(const short8*)(pa + 1536);
        f1_unit(u0, u1, u2, u3, wid, bufA);
      }
      __syncthreads();
      // steady: p=1..7, F1(half p) || F2(half p-1); uniform, rolled
#pragma unroll 1
      for (int p = 1; p < 8; ++p) {
        unsigned short* const wbuf = (p & 1) ? bufB : bufA;
        const unsigned short* const rbuf = (p & 1) ? bufA : bufB;
        const int q = p - 1;
        const int gu = p * 4 + wid;
        const unsigned short* pa = w1b + (size_t)gu * 2048 + (size_t)lane * 8;
        short8 u0 = *(const short8*)(pa);
        short8 u1 = *(const short8*)(pa + 512);
        short8 u2 = *(const short8*)(pa + 1024);
        short8 u3 = *(const short8*)(pa + 1536);
        short8 wA0 = *(const short8*)(w2b + (size_t)(ntA * 16 + q * 2) * 512 +
                                      (size_t)lane * 8);
        short8 wB0 = wA0;
        if (hasB2)
          wB0 = *(const short8*)(w2b + (size_t)(ntB * 16 + q * 2) * 512 +
                                 (size_t)lane * 8);
        f2_step(wA0, wB0, rbuf, 0);
        short8 wA1 = *(const short8*)(w2b +
                                      (size_t)(ntA * 16 + q * 2 + 1) * 512 +
                                      (size_t)lane * 8);
        short8 wB1 = wA1;
        if (hasB2)
          wB1 = *(const short8*)(w2b + (size_t)(ntB * 16 + q * 2 + 1) * 512 +
                                 (size_t)lane * 8);
        f1_unit(u0, u1, u2, u3, gu, wbuf);  // hides u*/wA1 latency
        f2_step(wA1, wB1, rbuf, 1);
        __syncthreads();
      }
      // epilogue: F2 half 7 (ksl 14,15) from bufB (written at p=7)
      {
        short8 wA0 = *(const short8*)(w2b + (size_t)(ntA * 16 + 14) * 512 +
                                      (size_t)lane * 8);
        short8 wB0 = wA0;
        if (hasB2)
          wB0 = *(const short8*)(w2b + (size_t)(ntB * 16 + 14) * 512 +
                                 (size_t)lane * 8);
        short8 wA1 = *(const short8*)(w2b + (size_t)(ntA * 16 + 15) * 512 +
                                      (size_t)lane * 8);
        short8 wB1 = wA1;
        if (hasB2)
          wB1 = *(const short8*)(w2b + (size_t)(ntB * 16 + 15) * 512 +
                                 (size_t)lane * 8);
        f2_step(wA0, wB0, bufB, 0);
        f2_step(wA1, wB1, bufB, 1);
      }
      __syncthreads();  // all F2 reads done before scr overwrite
      // FFN2 epilogue -> scr (overwrites dead FFN bufs)
#pragma unroll
      for (int idx = 0; idx < 2; ++idx) {
        const int nt = idx == 0 ? ntA : ntB;
        const int n0 = nt * 16 + quad * 4;
        if (nt < 7 && n0 < D) {
#pragma unroll
          for (int mt = 0; mt < 3; ++mt)
            *(floatx4*)(scr + (mt * 16 + l15) * D + n0) = facc[idx][mt];
        }
      }
    }
    __syncthreads();
    if (tid < 192)
      ln_rows(sXf + row_o * D, scr + row_o * D, g2 + lay * D, bt2 + lay * D,
              sA + row_o * LDA, ln_o, cnt_o);
    __syncthreads();
  }

  // ---- classifier (fp32 VALU, exact): reads sXf master directly ----
  if (tid < 160) {
    const int c = tid % 40, eg = tid / 40;
    float acc[4];
#pragma unroll
    for (int i = 0; i < 4; ++i) acc[i] = bfc[c];
    const floatx4* wr = (const floatx4*)(Wf + c * 300);
    for (int kq = 0; kq < 75; ++kq) {
      const floatx4 w4 = wr[kq];
#pragma unroll
      for (int i = 0; i < 4; ++i) {
        const floatx4 x4 = *(const floatx4*)(sXf + (eg * 4 + i) * 300 + kq * 4);
        acc[i] += w4.x * x4.x + w4.y * x4.y + w4.z * x4.z + w4.w * x4.w;
      }
    }
#pragma unroll
    for (int i = 0; i < 4; ++i)
      gout[((size_t)blk * NB + eg * 4 + i) * CLS + c] = acc[i];
  }
}

extern "C" void kernel_launch(void* const* d_in, const int* in_sizes, int n_in,
                              void* d_out, int out_size, void* d_ws,
                              size_t ws_size, hipStream_t stream) {
  const float* x   = (const float*)d_in[0];
  const float* We  = (const float*)d_in[3];
  const float* be  = (const float*)d_in[4];
  const float* pe  = (const float*)d_in[5];
  const float* Wq  = (const float*)d_in[6];
  const float* bq  = (const float*)d_in[7];
  const float* Wk  = (const float*)d_in[8];
  const float* bk  = (const float*)d_in[9];
  const float* Wv  = (const float*)d_in[10];
  const float* bv  = (const float*)d_in[11];
  const float* Wo  = (const float*)d_in[12];
  const float* bo  = (const float*)d_in[13];
  const float* g1  = (const float*)d_in[14];
  const float* bt1 = (const float*)d_in[15];
  const float* W1  = (const float*)d_in[16];
  const float* b1  = (const float*)d_in[17];
  const float* W2  = (const float*)d_in[18];
  const float* b2  = (const float*)d_in[19];
  const float* g2  = (const float*)d_in[20];
  const float* bt2 = (const float*)d_in[21];
  const float* Wf  = (const float*)d_in[22];
  const float* bf  = (const float*)d_in[23];
  float* out = (float*)d_out;
  unsigned short* ws = (unsigned short*)d_ws;

  prep_weights<<<710, 256, 0, stream>>>(Wq, Wk, Wv, Wo, W1, W2, We, ws);

  const int B = in_sizes[0] / (S * DIN);
  const int blocks = B / NB;  // 4096
  geomap_mfma<<<blocks, NT, 0, stream>>>(x, be, pe, bq, bk, bv, bo,
                                         g1, bt1, b1, b2, g2, bt2, Wf, bf,
                                         ws, out);
}

// Round 13
// 1202.362 us; speedup vs baseline: 1.1685x; 1.0726x over previous
//
#include <hip/hip_runtime.h>
#include <hip/hip_bf16.h>

// GeoMapNet fused forward, MFMA bf16, LDS-resident fp32 master (R19).
// R19 = R14 verbatim - the measured optimum (1201 us). Design-space map:
//  R7/R10 (+waves/+blocks), R8/R9/R11 (reg prefetch): ~84-arch-VGPR
//    spill cliff (unified 170/wave at (256,3) splits ~84 arch + ~84 acc).
//  R12 (barrier-free per-wave): 4x L2 weight amplification.
//  R17/R18 (FFN ping-pong, incl. fully clean v2): +3 barriers/layer cost
//    MORE than the weight-load latency they hide - at 3 blocks/CU,
//    cross-block wave overlap already covers it (m99/m131-140 lesson).
// R14's wins over the session-entry R6 (1367): s_setprio(1/0) around MFMA
// clusters (+ scheduler role diversity across 3 independent blocks/CU)
// and exp2-base softmax (scores pre-scaled by DH^-0.5*log2(e)).

typedef __attribute__((ext_vector_type(8))) short short8;   // 8 bf16
typedef __attribute__((ext_vector_type(4))) float floatx4;  // MFMA C/D

namespace {
constexpr int S = 3, DIN = 72, D = 100, FF = 512, L = 8, CLS = 40;
constexpr int NB = 16, R = 48, NT = 256;
constexpr int LDA = 136;   // sA row stride (shorts): 16B-aligned, bank-rotated
constexpr int LDH = 200;   // sH row stride (shorts): 400 B, rotate 4 banks
// DH^-0.5 * log2(e): softmax via exp2 (identical result, saves a mul/exp)
constexpr float SCALE_L2E = 0.45622024f;

// d_ws element offsets (bf16). Fragment block = 64 lanes x 8 bf16.
constexpr int PL_QKVO = 7 * 4 * 512;                 // per layer
constexpr int WQ_OFF = 0;
constexpr int WK_OFF = WQ_OFF + L * PL_QKVO;
constexpr int WV_OFF = WK_OFF + L * PL_QKVO;
constexpr int WO_OFF = WV_OFF + L * PL_QKVO;
constexpr int PL_W1 = 32 * 4 * 512;
constexpr int W1_OFF = WO_OFF + L * PL_QKVO;
constexpr int PL_W2 = 7 * 16 * 512;
constexpr int W2_OFF = W1_OFF + L * PL_W1;
constexpr int WE_OFF = W2_OFF + L * PL_W2;           // 7 nt x 3 ks
}  // namespace

#define MFMA_BF16 __builtin_amdgcn_mfma_f32_16x16x32_bf16

__device__ __forceinline__ unsigned short f2bf(float f) {  // RTNE (prep only)
  unsigned int u = __float_as_uint(f);
  u = u + 0x7fffu + ((u >> 16) & 1u);
  return (unsigned short)(u >> 16);
}

__device__ __forceinline__ unsigned pkbf(float a, float b) {  // packed cvt
  __hip_bfloat162 h = __float22bfloat162_rn(make_float2(a, b));
  return *reinterpret_cast<unsigned*>(&h);
}

__device__ __forceinline__ void st_bf4(unsigned short* p, floatx4 v) {
  *reinterpret_cast<uint2*>(p) = make_uint2(pkbf(v.x, v.y), pkbf(v.z, v.w));
}

__device__ __forceinline__ void load10(float* o, const unsigned short* p) {
  const unsigned* u = (const unsigned*)p;  // 4B-aligned (even col)
#pragma unroll
  for (int w = 0; w < 5; ++w) {
    unsigned x = u[w];
    o[2 * w] = __uint_as_float(x << 16);
    o[2 * w + 1] = __uint_as_float(x & 0xffff0000u);
  }
}

__device__ __forceinline__ void ldwf4(const unsigned short* base, short8* o) {
#pragma unroll
  for (int ks = 0; ks < 4; ++ks) o[ks] = *(const short8*)(base + ks * 512);
}

// LayerNorm over 48 rows of 100; 4 lanes/row (192 threads), vectorized.
// t = xrow + srow (residual); xrow = LN(t)*g+b (fp32 master, in-place safe:
// values cached in regs); also writes bf16 to the sA row.
__device__ __forceinline__ void ln_rows(float* xrow, const float* srow,
                                        const float* __restrict__ g,
                                        const float* __restrict__ b,
                                        unsigned short* sArow, int ln,
                                        int cnt) {
  floatx4 v[7];
  float sum = 0.f;
#pragma unroll
  for (int i = 0; i < 7; ++i)
    if (i < cnt) {
      const int col = i * 16 + ln * 4;
      floatx4 t = *(const floatx4*)(xrow + col) + *(const floatx4*)(srow + col);
      v[i] = t;
      sum += t.x + t.y + t.z + t.w;
    }
  sum += __shfl_xor(sum, 1, 4);
  sum += __shfl_xor(sum, 2, 4);
  const float mean = sum * 0.01f;
  float var = 0.f;
#pragma unroll
  for (int i = 0; i < 7; ++i)
    if (i < cnt) {
      floatx4 d = v[i] - mean;
      var += d.x * d.x + d.y * d.y + d.z * d.z + d.w * d.w;
    }
  var += __shfl_xor(var, 1, 4);
  var += __shfl_xor(var, 2, 4);
  const float rstd = rsqrtf(var * 0.01f + 1e-5f);
#pragma unroll
  for (int i = 0; i < 7; ++i)
    if (i < cnt) {
      const int col = i * 16 + ln * 4;
      floatx4 o = (v[i] - mean) * rstd * *(const floatx4*)(g + col) +
                  *(const floatx4*)(b + col);
      *(floatx4*)(xrow + col) = o;
      st_bf4(sArow + col, o);
    }
}

// ------------- weight pre-pack: fp32 row-major -> bf16 fragment blocks -----
__global__ void prep_weights(const float* __restrict__ Wq, const float* __restrict__ Wk,
                             const float* __restrict__ Wv, const float* __restrict__ Wo,
                             const float* __restrict__ W1, const float* __restrict__ W2,
                             const float* __restrict__ We,
                             unsigned short* __restrict__ ws) {
  const int gid = blockIdx.x * 256 + threadIdx.x;
  constexpr int T_QKVO = 8 * 7 * 4 * 64;  // 14336
  constexpr int T_W1 = 8 * 32 * 4 * 64;   // 65536
  constexpr int T_W2 = 8 * 7 * 16 * 64;   // 57344
  constexpr int T_WE = 7 * 3 * 64;        // 1344
  if (gid >= 4 * T_QKVO + T_W1 + T_W2 + T_WE) return;

  const float* src;
  unsigned short* dst;
  int within, ntc, ksc, N, Ksrc, lstride;
  if (gid < 4 * T_QKVO) {
    const int t = gid / T_QKVO;
    within = gid % T_QKVO;
    src = (t == 0 ? Wq : t == 1 ? Wk : t == 2 ? Wv : Wo);
    dst = ws + (t == 0 ? WQ_OFF : t == 1 ? WK_OFF : t == 2 ? WV_OFF : WO_OFF);
    ntc = 7; ksc = 4; N = 100; Ksrc = 100; lstride = 10000;
  } else if (gid < 4 * T_QKVO + T_W1) {
    within = gid - 4 * T_QKVO;
    src = W1; dst = ws + W1_OFF;
    ntc = 32; ksc = 4; N = 512; Ksrc = 100; lstride = 51200;
  } else if (gid < 4 * T_QKVO + T_W1 + T_W2) {
    within = gid - 4 * T_QKVO - T_W1;
    src = W2; dst = ws + W2_OFF;
    ntc = 7; ksc = 16; N = 100; Ksrc = 512; lstride = 51200;
  } else {
    within = gid - 4 * T_QKVO - T_W1 - T_W2;
    src = We; dst = ws + WE_OFF;
    ntc = 7; ksc = 3; N = 100; Ksrc = 72; lstride = 0;
  }
  const int lane = within & 63;
  int tmp = within >> 6;
  const int ks = tmp % ksc; tmp /= ksc;
  const int nt = tmp % ntc;
  const int lay = tmp / ntc;
  const int n = nt * 16 + (lane & 15);
  const int kb = ks * 32 + (lane >> 4) * 8;
  const float* sp = src + (size_t)lay * lstride + (size_t)n * Ksrc;
  unsigned short o[8];
#pragma unroll
  for (int j = 0; j < 8; ++j) {
    const int k = kb + j;
    float v = (n < N && k < Ksrc) ? sp[k] : 0.f;
    o[j] = f2bf(v);
  }
  uint4 pk = make_uint4((unsigned)o[0] | ((unsigned)o[1] << 16),
                        (unsigned)o[2] | ((unsigned)o[3] << 16),
                        (unsigned)o[4] | ((unsigned)o[5] << 16),
                        (unsigned)o[6] | ((unsigned)o[7] << 16));
  *reinterpret_cast<uint4*>(dst + (size_t)within * 8) = pk;
}

__global__ __launch_bounds__(NT, 3)
void geomap_mfma(const float* __restrict__ gx,
                 const float* __restrict__ be, const float* __restrict__ pe,
                 const float* __restrict__ bq, const float* __restrict__ bk,
                 const float* __restrict__ bv, const float* __restrict__ bo,
                 const float* __restrict__ g1, const float* __restrict__ bt1,
                 const float* __restrict__ b1, const float* __restrict__ b2,
                 const float* __restrict__ g2, const float* __restrict__ bt2,
                 const float* __restrict__ Wf, const float* __restrict__ bfc,
                 const unsigned short* __restrict__ ws,
                 float* __restrict__ gout) {
  // 51456 B -> 3 blocks/CU (3*51456 = 154368 <= 163840)
  __shared__ __align__(16) char smem[51456];
  unsigned short* sA = (unsigned short*)smem;            // [48][136]: X|V|ctx
  float* sXf = (float*)(smem + 13056);                   // [48][100] fp32 master
  unsigned short* sQ = (unsigned short*)(smem + 32256);  // [48][100] bf16
  unsigned short* sK = (unsigned short*)(smem + 41856);  // [48][100]
  float* scr = (float*)(smem + 32256);                   // [48][100] (alias C)
  unsigned short* sH = (unsigned short*)(smem + 32256);  // [48][200] (alias C)

  const int tid = threadIdx.x;
  const int lane = tid & 63;
  const int wid = tid >> 6;
  const int l15 = lane & 15;
  const int quad = lane >> 4;
  const int blk = blockIdx.x;

  const int row_o = tid >> 2, ln_o = tid & 3;  // LN job (threads < 192)
  const int cnt_o = (ln_o == 0) ? 7 : 6;

  // ---- zero sA (pad cols stay 0 forever), then stage x as bf16 ----
  for (int i = tid; i < R * LDA / 2; i += NT) ((unsigned*)sA)[i] = 0u;
  __syncthreads();
  for (int i = tid; i < R * DIN / 2; i += NT) {
    const int row = i / 36, c = (i % 36) * 2;
    const float2 f2 = *(const float2*)(gx + ((size_t)blk * R + row) * DIN + c);
    ((unsigned*)sA)[row * (LDA / 2) + (c >> 1)] = pkbf(f2.x, f2.y);
  }
  __syncthreads();

  // ---- embedding via MFMA: sXf/sA = x @ We^T + be + pe ----
  {
    short8 xe[3][3];
#pragma unroll
    for (int mt = 0; mt < 3; ++mt)
#pragma unroll
      for (int ks = 0; ks < 3; ++ks)
        xe[mt][ks] = *(const short8*)(sA + (mt * 16 + l15) * LDA + ks * 32 + quad * 8);
    __syncthreads();  // all x-frags in regs before epilogue overwrites sA
    for (int nt = wid; nt < 7; nt += 4) {
      const unsigned short* wb = ws + WE_OFF + (size_t)(nt * 3) * 512 + (size_t)lane * 8;
      short8 w0 = *(const short8*)(wb);
      short8 w1 = *(const short8*)(wb + 512);
      short8 w2 = *(const short8*)(wb + 1024);
      const int n0 = nt * 16 + quad * 4;
      floatx4 a[3];
      __builtin_amdgcn_s_setprio(1);
#pragma unroll
      for (int mt = 0; mt < 3; ++mt) {
        a[mt] = floatx4{0.f, 0.f, 0.f, 0.f};
        a[mt] = MFMA_BF16(w0, xe[mt][0], a[mt], 0, 0, 0);
        a[mt] = MFMA_BF16(w1, xe[mt][1], a[mt], 0, 0, 0);
        a[mt] = MFMA_BF16(w2, xe[mt][2], a[mt], 0, 0, 0);
      }
      __builtin_amdgcn_s_setprio(0);
      if (n0 < D) {
        const floatx4 bev = *(const floatx4*)(be + n0);
#pragma unroll
        for (int mt = 0; mt < 3; ++mt) {
          const int row = mt * 16 + l15;
          const int s = row % 3;
          const floatx4 pev = *(const floatx4*)(pe + s * D + n0);
          const floatx4 o = a[mt] + bev + pev;
          *(floatx4*)(sXf + row * D + n0) = o;
          st_bf4(sA + row * LDA + n0, o);
        }
      }
    }
  }
  __syncthreads();

  for (int lay = 0; lay < L; ++lay) {
    // ---- QKV: 21 units; V lands in sA rows (X dead after xf capture) ----
    {
      short8 xf[3][4];
#pragma unroll
      for (int mt = 0; mt < 3; ++mt)
#pragma unroll
        for (int ks = 0; ks < 4; ++ks)
          xf[mt][ks] = *(const short8*)(sA + (mt * 16 + l15) * LDA + ks * 32 + quad * 8);
      __syncthreads();  // every wave has X frags; V may overwrite sA now
      const unsigned short* wbase[3] = {ws + WQ_OFF + lay * PL_QKVO,
                                        ws + WK_OFF + lay * PL_QKVO,
                                        ws + WV_OFF + lay * PL_QKVO};
      for (int u = wid; u < 21; u += 4) {
        const int mat = u / 7, nt = u % 7;
        short8 wf[4];
        ldwf4(wbase[mat] + (size_t)nt * 2048 + (size_t)lane * 8, wf);
        const int n0 = nt * 16 + quad * 4;
        floatx4 bias = {0.f, 0.f, 0.f, 0.f};
        const float* bsrc = (mat == 0 ? bq : mat == 1 ? bk : bv) + lay * D;
        if (n0 < D) bias = *(const floatx4*)(bsrc + n0);
        floatx4 a0 = bias, a1 = bias, a2 = bias;
        __builtin_amdgcn_s_setprio(1);
#pragma unroll
        for (int ks = 0; ks < 4; ++ks) {
          a0 = MFMA_BF16(wf[ks], xf[0][ks], a0, 0, 0, 0);
          a1 = MFMA_BF16(wf[ks], xf[1][ks], a1, 0, 0, 0);
          a2 = MFMA_BF16(wf[ks], xf[2][ks], a2, 0, 0, 0);
        }
        __builtin_amdgcn_s_setprio(0);
        if (n0 < D) {
          const floatx4 av[3] = {a0, a1, a2};
#pragma unroll
          for (int mt = 0; mt < 3; ++mt) {
            const int row = mt * 16 + l15;
            if (mat == 0) st_bf4(sQ + row * 100 + n0, av[mt]);
            else if (mat == 1) st_bf4(sK + row * 100 + n0, av[mt]);
            else st_bf4(sA + row * LDA + n0, av[mt]);  // V into sA
          }
        }
      }
    }
    __syncthreads();

    // ---- attention: 160 jobs = (e,h); V in sA, ctx written in-place ----
    if (tid < 160) {
      const int e = tid / 10, h = tid % 10;
      const unsigned short* Qe = sQ + e * 300;  // stride-100 rows -> flat 300
      const unsigned short* Ke = sK + e * 300;
      float Kv[3][10];
#pragma unroll
      for (int t = 0; t < 3; ++t) load10(Kv[t], Ke + h * 30 + t * 10);
      float p[3][3];
#pragma unroll
      for (int sq = 0; sq < 3; ++sq) {
        float q[10];
        load10(q, Qe + h * 30 + sq * 10);
        float sc[3];
#pragma unroll
        for (int t = 0; t < 3; ++t) {
          float s0 = 0.f;
#pragma unroll
          for (int j = 0; j < 10; ++j) s0 += q[j] * Kv[t][j];
          sc[t] = s0 * SCALE_L2E;  // exp2-base softmax (identical result)
        }
        const float m = fmaxf(sc[0], fmaxf(sc[1], sc[2]));
        float p0 = exp2f(sc[0] - m), p1 = exp2f(sc[1] - m), p2 = exp2f(sc[2] - m);
        const float inv = 1.f / (p0 + p1 + p2);
        p[sq][0] = p0 * inv; p[sq][1] = p1 * inv; p[sq][2] = p2 * inv;
      }
      float ctx[3][10];
#pragma unroll
      for (int sq = 0; sq < 3; ++sq)
#pragma unroll
        for (int j = 0; j < 10; ++j) ctx[sq][j] = 0.f;
#pragma unroll
      for (int t = 0; t < 3; ++t) {
        const int pv = h * 30 + t * 10;
        float vv[10];
        load10(vv, sA + (e * 3 + pv / 100) * LDA + (pv % 100));
#pragma unroll
        for (int sq = 0; sq < 3; ++sq)
#pragma unroll
          for (int j = 0; j < 10; ++j) ctx[sq][j] += p[sq][t] * vv[j];
      }
#pragma unroll
      for (int sq = 0; sq < 3; ++sq) {
        const int pq = h * 30 + sq * 10;
        unsigned* dp = (unsigned*)(sA + (e * 3 + pq / 100) * LDA + (pq % 100));
#pragma unroll
        for (int w = 0; w < 5; ++w)
          dp[w] = pkbf(ctx[sq][2 * w], ctx[sq][2 * w + 1]);
      }
    }
    __syncthreads();

    // ---- Wo -> scr (overwrites dead sQ/sK; residual added in LN1) ----
    {
      short8 cf[3][4];
#pragma unroll
      for (int mt = 0; mt < 3; ++mt)
#pragma unroll
        for (int ks = 0; ks < 4; ++ks)
          cf[mt][ks] = *(const short8*)(sA + (mt * 16 + l15) * LDA + ks * 32 + quad * 8);
      const unsigned short* wbase = ws + WO_OFF + lay * PL_QKVO;
      for (int u = wid; u < 7; u += 4) {
        short8 wf[4];
        ldwf4(wbase + (size_t)u * 2048 + (size_t)lane * 8, wf);
        const int n0 = u * 16 + quad * 4;
        floatx4 bias = {0.f, 0.f, 0.f, 0.f};
        if (n0 < D) bias = *(const floatx4*)(bo + lay * D + n0);
        floatx4 a0 = bias, a1 = bias, a2 = bias;
        __builtin_amdgcn_s_setprio(1);
#pragma unroll
        for (int ks = 0; ks < 4; ++ks) {
          a0 = MFMA_BF16(wf[ks], cf[0][ks], a0, 0, 0, 0);
          a1 = MFMA_BF16(wf[ks], cf[1][ks], a1, 0, 0, 0);
          a2 = MFMA_BF16(wf[ks], cf[2][ks], a2, 0, 0, 0);
        }
        __builtin_amdgcn_s_setprio(0);
        if (n0 < D) {
          const floatx4 av[3] = {a0, a1, a2};
#pragma unroll
          for (int mt = 0; mt < 3; ++mt)
            *(floatx4*)(scr + (mt * 16 + l15) * D + n0) = av[mt];
        }
      }
    }
    __syncthreads();
    if (tid < 192)
      ln_rows(sXf + row_o * D, scr + row_o * D, g1 + lay * D, bt1 + lay * D,
              sA + row_o * LDA, ln_o, cnt_o);
    __syncthreads();

    // ---- FFN: 3 chunks {192,192,128}; sH overwrites dead scr ----
    {
      short8 ff[3][4];
#pragma unroll
      for (int mt = 0; mt < 3; ++mt)
#pragma unroll
        for (int ks = 0; ks < 4; ++ks)
          ff[mt][ks] = *(const short8*)(sA + (mt * 16 + l15) * LDA + ks * 32 + quad * 8);
      floatx4 facc[2][3];
      const int ntA = wid, ntB = wid + 4;  // FFN2 output tiles (ntB if < 7)
#pragma unroll
      for (int idx = 0; idx < 2; ++idx) {
        const int nt = idx == 0 ? ntA : ntB;
        const int n0 = nt * 16 + quad * 4;
        floatx4 bias = {0.f, 0.f, 0.f, 0.f};
        if (nt < 7 && n0 < D) bias = *(const floatx4*)(b2 + lay * D + n0);
#pragma unroll
        for (int mt = 0; mt < 3; ++mt) facc[idx][mt] = bias;
      }
      const unsigned short* w1b = ws + W1_OFF + (size_t)lay * PL_W1;
      const unsigned short* w2b = ws + W2_OFF + (size_t)lay * PL_W2;

#pragma unroll
      for (int c = 0; c < 3; ++c) {
        const int base_nt = c * 12;               // chunk hidden base / 16
        const int cnt_nt = (c == 2) ? 8 : 12;     // hidden tiles this chunk
        const int kb = c * 6, ke = kb + ((c == 2) ? 4 : 6);  // FFN2 ks range
        // FFN1: 2-3 units per wave
        for (int l = wid; l < cnt_nt; l += 4) {
          const int ntg = base_nt + l;
          short8 wf[4];
          ldwf4(w1b + (size_t)ntg * 2048 + (size_t)lane * 8, wf);
          const floatx4 b1v = *(const floatx4*)(b1 + lay * FF + ntg * 16 + quad * 4);
          floatx4 a0 = b1v, a1 = b1v, a2 = b1v;
          __builtin_amdgcn_s_setprio(1);
#pragma unroll
          for (int ks = 0; ks < 4; ++ks) {
            a0 = MFMA_BF16(wf[ks], ff[0][ks], a0, 0, 0, 0);
            a1 = MFMA_BF16(wf[ks], ff[1][ks], a1, 0, 0, 0);
            a2 = MFMA_BF16(wf[ks], ff[2][ks], a2, 0, 0, 0);
          }
          __builtin_amdgcn_s_setprio(0);
          const int nloc = l * 16 + quad * 4;
          const floatx4 av[3] = {a0, a1, a2};
#pragma unroll
          for (int mt = 0; mt < 3; ++mt) {
            const int row = mt * 16 + l15;
            floatx4 r;
            r.x = fmaxf(av[mt].x, 0.f); r.y = fmaxf(av[mt].y, 0.f);
            r.z = fmaxf(av[mt].z, 0.f); r.w = fmaxf(av[mt].w, 0.f);
            st_bf4(sH + row * LDH + nloc, r);
          }
        }
        __syncthreads();
        // FFN2: wave's 1-2 nt units share hf reads; rolling wf pair prefetch
        short8 wA = *(const short8*)(w2b + (size_t)(ntA * 16 + kb) * 512 + (size_t)lane * 8);
        short8 wB = wA;
        if (ntB < 7)
          wB = *(const short8*)(w2b + (size_t)(ntB * 16 + kb) * 512 + (size_t)lane * 8);
        for (int ksl = kb; ksl < ke; ++ksl) {
          short8 nA = wA, nB = wB;
          if (ksl + 1 < ke) {
            nA = *(const short8*)(w2b + (size_t)(ntA * 16 + ksl + 1) * 512 + (size_t)lane * 8);
            if (ntB < 7)
              nB = *(const short8*)(w2b + (size_t)(ntB * 16 + ksl + 1) * 512 + (size_t)lane * 8);
          }
          short8 hf[3];
#pragma unroll
          for (int mt = 0; mt < 3; ++mt)
            hf[mt] = *(const short8*)(sH + (mt * 16 + l15) * LDH + (ksl - kb) * 32 + quad * 8);
          __builtin_amdgcn_s_setprio(1);
#pragma unroll
          for (int mt = 0; mt < 3; ++mt)
            facc[0][mt] = MFMA_BF16(wA, hf[mt], facc[0][mt], 0, 0, 0);
          if (ntB < 7) {
#pragma unroll
            for (int mt = 0; mt < 3; ++mt)
              facc[1][mt] = MFMA_BF16(wB, hf[mt], facc[1][mt], 0, 0, 0);
          }
          __builtin_amdgcn_s_setprio(0);
          wA = nA; wB = nB;
        }
        __syncthreads();  // sH consumed; next FFN1 / scr write safe
      }
      // FFN2 epilogue -> scr (overwrites dead sH)
#pragma unroll
      for (int idx = 0; idx < 2; ++idx) {
        const int nt = idx == 0 ? ntA : ntB;
        const int n0 = nt * 16 + quad * 4;
        if (nt < 7 && n0 < D) {
#pragma unroll
          for (int mt = 0; mt < 3; ++mt)
            *(floatx4*)(scr + (mt * 16 + l15) * D + n0) = facc[idx][mt];
        }
      }
    }
    __syncthreads();
    if (tid < 192)
      ln_rows(sXf + row_o * D, scr + row_o * D, g2 + lay * D, bt2 + lay * D,
              sA + row_o * LDA, ln_o, cnt_o);
    __syncthreads();
  }

  // ---- classifier (fp32 VALU, exact): reads sXf master directly ----
  if (tid < 160) {
    const int c = tid % 40, eg = tid / 40;
    float acc[4];
#pragma unroll
    for (int i = 0; i < 4; ++i) acc[i] = bfc[c];
    const floatx4* wr = (const floatx4*)(Wf + c * 300);
    for (int kq = 0; kq < 75; ++kq) {
      const floatx4 w4 = wr[kq];
#pragma unroll
      for (int i = 0; i < 4; ++i) {
        const floatx4 x4 = *(const floatx4*)(sXf + (eg * 4 + i) * 300 + kq * 4);
        acc[i] += w4.x * x4.x + w4.y * x4.y + w4.z * x4.z + w4.w * x4.w;
      }
    }
#pragma unroll
    for (int i = 0; i < 4; ++i)
      gout[((size_t)blk * NB + eg * 4 + i) * CLS + c] = acc[i];
  }
}

extern "C" void kernel_launch(void* const* d_in, const int* in_sizes, int n_in,
                              void* d_out, int out_size, void* d_ws,
                              size_t ws_size, hipStream_t stream) {
  const float* x   = (const float*)d_in[0];
  const float* We  = (const float*)d_in[3];
  const float* be  = (const float*)d_in[4];
  const float* pe  = (const float*)d_in[5];
  const float* Wq  = (const float*)d_in[6];
  const float* bq  = (const float*)d_in[7];
  const float* Wk  = (const float*)d_in[8];
  const float* bk  = (const float*)d_in[9];
  const float* Wv  = (const float*)d_in[10];
  const float* bv  = (const float*)d_in[11];
  const float* Wo  = (const float*)d_in[12];
  const float* bo  = (const float*)d_in[13];
  const float* g1  = (const float*)d_in[14];
  const float* bt1 = (const float*)d_in[15];
  const float* W1  = (const float*)d_in[16];
  const float* b1  = (const float*)d_in[17];
  const float* W2  = (const float*)d_in[18];
  const float* b2  = (const float*)d_in[19];
  const float* g2  = (const float*)d_in[20];
  const float* bt2 = (const float*)d_in[21];
  const float* Wf  = (const float*)d_in[22];
  const float* bf  = (const float*)d_in[23];
  float* out = (float*)d_out;
  unsigned short* ws = (unsigned short*)d_ws;

  prep_weights<<<710, 256, 0, stream>>>(Wq, Wk, Wv, Wo, W1, W2, We, ws);

  const int B = in_sizes[0] / (S * DIN);
  const int blocks = B / NB;  // 4096
  geomap_mfma<<<blocks, NT, 0, stream>>>(x, be, pe, bq, bk, bv, bo,
                                         g1, bt1, b1, b2, g2, bt2, Wf, bf,
                                         ws, out);
}